// Round 1
// baseline (493.170 us; speedup 1.0000x reference)
//
#include <hip/hip_runtime.h>
#include <hip/hip_bf16.h>

#define NB 4
#define CI 128
#define CO 128
#define HH 128
#define WW 128
#define HW 16384
#define KK 9

typedef __attribute__((ext_vector_type(4))) float f32x4;
typedef __attribute__((ext_vector_type(8))) short bf16x8;

static __device__ __forceinline__ unsigned short f2bf(float v) {
  __hip_bfloat16 h = __float2bfloat16(v);
  return *reinterpret_cast<const unsigned short*>(&h);
}

// ---------------- Kernel A: offset conv (f32), 16x16 tile, 256 blocks ----------------
__global__ __launch_bounds__(256) void k_offconv(
    const float* __restrict__ x, const float* __restrict__ w_off,
    const float* __restrict__ b_off, float* __restrict__ offs) {
  __shared__ float tile[18 * 18];
  const int bid = blockIdx.x;  // 4 * 64
  const int b = bid >> 6;
  const int rem = bid & 63;
  const int h0 = (rem >> 3) << 4;
  const int w0 = (rem & 7) << 4;
  const int t = threadIdx.x;
  const int ph = t >> 4, pw = t & 15;
  float acc[18];
#pragma unroll
  for (int i = 0; i < 18; ++i) acc[i] = 0.f;
  const float* xb = x + (size_t)b * CI * HW;
  for (int ci = 0; ci < CI; ++ci) {
    for (int i = t; i < 324; i += 256) {
      int r = i / 18, c = i - r * 18;
      int gh = h0 - 1 + r, gw = w0 - 1 + c;
      float v = 0.f;
      if ((unsigned)gh < 128u && (unsigned)gw < 128u) v = xb[ci * HW + gh * WW + gw];
      tile[i] = v;
    }
    __syncthreads();
    float nb[9];
#pragma unroll
    for (int dy = 0; dy < 3; ++dy)
#pragma unroll
      for (int dx = 0; dx < 3; ++dx) nb[dy * 3 + dx] = tile[(ph + dy) * 18 + pw + dx];
    const float* wp = w_off + ci * 9;
#pragma unroll
    for (int oc = 0; oc < 18; ++oc) {
#pragma unroll
      for (int tap = 0; tap < 9; ++tap)
        acc[oc] = fmaf(nb[tap], wp[oc * (CI * 9) + tap], acc[oc]);
    }
    __syncthreads();
  }
  const int h = h0 + ph, w = w0 + pw;
#pragma unroll
  for (int oc = 0; oc < 18; ++oc)
    offs[((size_t)(b * 18 + oc)) * HW + h * WW + w] = acc[oc] + b_off[oc];
}

// ---------------- Kernel A2: w_dcn f32 -> bf16, layout [tap][co][ci] ----------------
__global__ __launch_bounds__(256) void k_wprep(const float* __restrict__ w,
                                               unsigned short* __restrict__ wT) {
  int i = blockIdx.x * 256 + threadIdx.x;
  if (i >= CO * CI * KK) return;
  int k = i % KK;
  int ci = (i / KK) & 127;
  int co = i / (KK * CI);
  wT[((size_t)k * CO + co) * CI + ci] = f2bf(w[i]);
}

// ---------------- Kernel B: fused deformable sampling + bf16 MFMA GEMM ----------------
// tile: 4(h) x 16(w) pixels, all 128 CO. 256 threads = 4 waves.
// waves split N (32 co each); M=64 px = 4 mfrags; K = 9 taps x 128 ci, K-step 32.
__global__ __launch_bounds__(256) void k_main(
    const float* __restrict__ x, const float* __restrict__ offs,
    const unsigned short* __restrict__ wT, float* __restrict__ outp,
    float* __restrict__ stats) {
  __shared__ float xst[32 * 288];        // 32 ci x (12 rows x 24 cols), halo 4
  __shared__ float scoord[KK * 64 * 2];  // ys,xs per (tap,px)
  __shared__ __align__(16) unsigned char samp[64 * 32 * 2];  // bf16 [px][ci_local], XOR-swizzled

  const int bid = blockIdx.x;  // 1024
  const int b = bid >> 8;
  const int rem = bid & 255;
  const int h0 = (rem >> 3) * 4;
  const int w0 = (rem & 7) * 16;
  const int t = threadIdx.x;
  const int l = t & 63;
  const int wv = t >> 6;
  const int colc = l & 15;
  const int kg = l >> 4;
  const int px_s = l;

  // phase 0: coords for all 9 taps
  for (int i = t; i < KK * 64; i += 256) {
    int tap = i >> 6, px = i & 63;
    int h = h0 + (px >> 4), w = w0 + (px & 15);
    float dy = offs[((size_t)(b * 18 + 2 * tap)) * HW + h * WW + w];
    float dx = offs[((size_t)(b * 18 + 2 * tap + 1)) * HW + h * WW + w];
    scoord[i * 2] = (float)(h - 1 + tap / 3) + dy;
    scoord[i * 2 + 1] = (float)(w - 1 + tap % 3) + dx;
  }

  f32x4 acc[4][2];
#pragma unroll
  for (int mf = 0; mf < 4; ++mf)
#pragma unroll
    for (int nf = 0; nf < 2; ++nf) acc[mf][nf] = (f32x4){0.f, 0.f, 0.f, 0.f};

  __syncthreads();

#pragma unroll 1
  for (int cig = 0; cig < 4; ++cig) {
    // stage 32 ci of x into LDS (zero-padded halo)
    const float* xb = x + (size_t)b * CI * HW + (size_t)cig * 32 * HW;
    for (int j = t; j < 32 * 288; j += 256) {
      int ci = j / 288;
      int e = j - ci * 288;
      int r = e / 24;
      int c = e - r * 24;
      int gh = h0 - 4 + r, gw = w0 - 4 + c;
      float v = 0.f;
      if ((unsigned)gh < 128u && (unsigned)gw < 128u) v = xb[ci * HW + gh * WW + gw];
      xst[j] = v;
    }
    __syncthreads();

#pragma unroll 1
    for (int tap = 0; tap < KK; ++tap) {
      // --- sampling: each wave covers all 64 px, ci pairs {2wv,2wv+1}+8it ---
      float2 c2 = *(const float2*)&scoord[(tap * 64 + px_s) * 2];
      float ysv = c2.x, xsv = c2.y;
      float y0f = floorf(ysv), x0f = floorf(xsv);
      float wy = ysv - y0f, wx = xsv - x0f;
      int iy0 = (int)y0f, ix0 = (int)x0f;
      bool vy0 = (unsigned)iy0 < 128u;
      bool vy1 = (unsigned)(iy0 + 1) < 128u;
      bool vx0 = (unsigned)ix0 < 128u;
      bool vx1 = (unsigned)(ix0 + 1) < 128u;
      float wy0 = 1.f - wy, wx0 = 1.f - wx;
      float w00 = wy0 * wx0 * ((vy0 & vx0) ? 1.f : 0.f);
      float w01 = wy0 * wx * ((vy0 & vx1) ? 1.f : 0.f);
      float w10 = wy * wx0 * ((vy1 & vx0) ? 1.f : 0.f);
      float w11 = wy * wx * ((vy1 & vx1) ? 1.f : 0.f);
      int rs = min(max(iy0 - h0 + 4, 0), 10);
      int cs = min(max(ix0 - w0 + 4, 0), 22);
      int sb = rs * 24 + cs;
#pragma unroll
      for (int it = 0; it < 4; ++it) {
        int cl = wv * 2 + it * 8;
        const float* r0 = &xst[cl * 288 + sb];
        const float* r1 = r0 + 288;
        float va = w00 * r0[0] + w01 * r0[1] + w10 * r0[24] + w11 * r0[25];
        float vb = w00 * r1[0] + w01 * r1[1] + w10 * r1[24] + w11 * r1[25];
        unsigned int pk = ((unsigned int)f2bf(vb) << 16) | (unsigned int)f2bf(va);
        int bo = (px_s * 64 + cl * 2) ^ ((px_s & 7) << 4);
        *(unsigned int*)(samp + bo) = pk;
      }
      __syncthreads();
      // --- MFMA: one K=32 step; A row=lane&15 (px), k=(lane>>4)*8+i (ci) ---
      bf16x8 afr[4];
#pragma unroll
      for (int mf = 0; mf < 4; ++mf) {
        int px = mf * 16 + colc;
        int bo = (px * 64 + kg * 16) ^ ((px & 7) << 4);
        afr[mf] = *(const bf16x8*)(samp + bo);
      }
#pragma unroll
      for (int nf = 0; nf < 2; ++nf) {
        int co = wv * 32 + nf * 16 + colc;
        bf16x8 bfr = *(const bf16x8*)(wT + ((size_t)(tap * CO + co)) * CI + cig * 32 + kg * 8);
#pragma unroll
        for (int mf = 0; mf < 4; ++mf)
          acc[mf][nf] = __builtin_amdgcn_mfma_f32_16x16x32_bf16(afr[mf], bfr, acc[mf][nf], 0, 0, 0);
      }
      __syncthreads();
    }
  }

  // epilogue: BN partial stats + store pre-BN out
#pragma unroll
  for (int nf = 0; nf < 2; ++nf) {
    float s = 0.f, sq = 0.f;
#pragma unroll
    for (int mf = 0; mf < 4; ++mf)
#pragma unroll
      for (int r = 0; r < 4; ++r) {
        float v = acc[mf][nf][r];
        s += v;
        sq += v * v;
      }
    s += __shfl_xor(s, 16);
    s += __shfl_xor(s, 32);
    sq += __shfl_xor(sq, 16);
    sq += __shfl_xor(sq, 32);
    if (kg == 0) {
      int co = wv * 32 + nf * 16 + colc;
      atomicAdd(&stats[co], s);
      atomicAdd(&stats[CO + co], sq);
    }
  }
  const size_t ob = (size_t)b * CO * HW;
#pragma unroll
  for (int mf = 0; mf < 4; ++mf) {
#pragma unroll
    for (int nf = 0; nf < 2; ++nf) {
      int co = wv * 32 + nf * 16 + colc;
      *(f32x4*)&outp[ob + (size_t)co * HW + (h0 + mf) * WW + w0 + kg * 4] = acc[mf][nf];
    }
  }
}

// ---------------- Kernel C: fold stats -> per-channel scale/shift ----------------
__global__ void k_stats(const float* __restrict__ stats, const float* __restrict__ gamma,
                        const float* __restrict__ beta, float* __restrict__ sc) {
  int co = threadIdx.x;
  const float inv = 1.f / 65536.f;
  float mean = stats[co] * inv;
  float var = stats[CO + co] * inv - mean * mean;
  float scale = rsqrtf(var + 1e-3f) * gamma[co];
  sc[co] = scale;
  sc[CO + co] = beta[co] - mean * scale;
}

// ---------------- Kernel D: in-place BN apply + ReLU (float4) ----------------
__global__ __launch_bounds__(256) void k_bn(float* __restrict__ outp,
                                            const float* __restrict__ sc) {
  int i = blockIdx.x * 256 + threadIdx.x;  // f32x4 index, 2097152 total
  f32x4 v = ((const f32x4*)outp)[i];
  int co = (i >> 12) & 127;
  float scale = sc[co], shift = sc[CO + co];
#pragma unroll
  for (int j = 0; j < 4; ++j) {
    float y = v[j] * scale + shift;
    v[j] = y > 0.f ? y : 0.f;
  }
  ((f32x4*)outp)[i] = v;
}

extern "C" void kernel_launch(void* const* d_in, const int* in_sizes, int n_in,
                              void* d_out, int out_size, void* d_ws, size_t ws_size,
                              hipStream_t stream) {
  const float* x = (const float*)d_in[0];
  const float* w_off = (const float*)d_in[1];
  const float* b_off = (const float*)d_in[2];
  const float* w_dcn = (const float*)d_in[3];
  const float* gamma = (const float*)d_in[4];
  const float* beta = (const float*)d_in[5];
  float* out = (float*)d_out;
  char* ws = (char*)d_ws;

  // ws layout: wT bf16 [0, 294912); offs f32 [294912, 5013504);
  //            stats f32 [5013504, 5014528); scale/shift [5014528, 5015552)
  unsigned short* wT = (unsigned short*)(ws);
  float* offs = (float*)(ws + 294912);
  float* stats = (float*)(ws + 5013504);
  float* sc = (float*)(ws + 5014528);

  hipMemsetAsync(stats, 0, 1024, stream);
  k_offconv<<<256, 256, 0, stream>>>(x, w_off, b_off, offs);
  k_wprep<<<576, 256, 0, stream>>>(w_dcn, wT);
  k_main<<<1024, 256, 0, stream>>>(x, offs, wT, out, stats);
  k_stats<<<1, 128, 0, stream>>>(stats, gamma, beta, sc);
  k_bn<<<8192, 256, 0, stream>>>(out, sc);
}

// Round 2
// 354.402 us; speedup vs baseline: 1.3916x; 1.3916x over previous
//
#include <hip/hip_runtime.h>
#include <hip/hip_bf16.h>

#define NB 4
#define CI 128
#define CO 128
#define HH 128
#define WW 128
#define HW 16384
#define KK 9

typedef __attribute__((ext_vector_type(4))) float f32x4;
typedef __attribute__((ext_vector_type(8))) short bf16x8;

static __device__ __forceinline__ unsigned short f2bf(float v) {
  __hip_bfloat16 h = __float2bfloat16(v);
  return *reinterpret_cast<const unsigned short*>(&h);
}

// ---------------- Kernel A: offset conv via MFMA ----------------
// GEMM: M = 64 px/block, N = 32 (18 valid oc), K = 1152 (9 tap x 128 ci).
// 4 waves split M (wave = tile row). Same A-swizzle as k_main.
__global__ __launch_bounds__(256) void k_offconv_mfma(
    const float* __restrict__ x, const unsigned short* __restrict__ wT2,
    const float* __restrict__ b_off, float* __restrict__ offs) {
  __shared__ float xtile[32 * 144];  // 32 ci x (6 rows x 24 cols), halo 1
  __shared__ __align__(16) unsigned char samp9[9 * 64 * 64];  // bf16 [tap][px][ci32], swizzled

  const int bid = blockIdx.x;  // 1024
  const int b = bid >> 8;
  const int rem = bid & 255;
  const int h0 = (rem >> 3) * 4;
  const int w0 = (rem & 7) * 16;
  const int t = threadIdx.x;
  const int l = t & 63;
  const int wv = t >> 6;
  const int colc = l & 15;
  const int kg = l >> 4;
  const int px = l;                         // build-phase pixel
  const int rb = (px >> 4) * 24 + (px & 15);  // tile-local (row,col) base

  f32x4 acc2[2];
  acc2[0] = (f32x4){0.f, 0.f, 0.f, 0.f};
  acc2[1] = (f32x4){0.f, 0.f, 0.f, 0.f};

#pragma unroll 1
  for (int cig = 0; cig < 4; ++cig) {
    // stage 32 ci, halo-1 tile (6 x 24, cols >=18 zero)
    const float* xb = x + (size_t)b * CI * HW + (size_t)cig * 32 * HW;
    for (int j = t; j < 32 * 144; j += 256) {
      int ci = j / 144;
      int e = j - ci * 144;
      int r = e / 24;
      int c = e - r * 24;
      int gh = h0 - 1 + r, gw = w0 - 1 + c;
      float v = 0.f;
      if (c < 18 && (unsigned)gh < 128u && (unsigned)gw < 128u) v = xb[ci * HW + gh * WW + gw];
      xtile[j] = v;
    }
    __syncthreads();

    // build im2col A for all 9 taps, bf16, XOR-swizzled rows of 64B
#pragma unroll
    for (int tap = 0; tap < KK; ++tap) {
      const int d = (tap / 3) * 24 + (tap % 3);
#pragma unroll
      for (int it = 0; it < 4; ++it) {
        int cl = wv * 2 + it * 8;
        float va = xtile[cl * 144 + rb + d];
        float vb = xtile[(cl + 1) * 144 + rb + d];
        unsigned int pk = ((unsigned int)f2bf(vb) << 16) | (unsigned int)f2bf(va);
        int bo = tap * 4096 + ((px * 64 + cl * 2) ^ ((px & 7) << 4));
        *(unsigned int*)(samp9 + bo) = pk;
      }
    }
    __syncthreads();

    // MFMA: wave wv owns tile row wv (px = wv*16 + m)
#pragma unroll
    for (int tap = 0; tap < KK; ++tap) {
      int apx = wv * 16 + colc;
      int bo = tap * 4096 + ((apx * 64 + kg * 16) ^ ((apx & 7) << 4));
      bf16x8 afr = *(const bf16x8*)(samp9 + bo);
#pragma unroll
      for (int nf = 0; nf < 2; ++nf) {
        int co = nf * 16 + colc;
        bf16x8 bfr = *(const bf16x8*)(wT2 + ((size_t)(tap * 32 + co)) * CI + cig * 32 + kg * 8);
        acc2[nf] = __builtin_amdgcn_mfma_f32_16x16x32_bf16(afr, bfr, acc2[nf], 0, 0, 0);
      }
    }
    __syncthreads();
  }

  // epilogue: D row m = kg*4+r -> w; col n = colc -> oc; wave -> h row
#pragma unroll
  for (int nf = 0; nf < 2; ++nf) {
    int oc = nf * 16 + colc;
    if (oc < 18) {
      float bo_ = b_off[oc];
      f32x4 v;
#pragma unroll
      for (int r = 0; r < 4; ++r) v[r] = acc2[nf][r] + bo_;
      *(f32x4*)&offs[((size_t)(b * 18 + oc)) * HW + (h0 + wv) * WW + w0 + kg * 4] = v;
    }
  }
}

// ---------------- Kernel A2: w_dcn f32 -> bf16, layout [tap][co][ci] ----------------
__global__ __launch_bounds__(256) void k_wprep(const float* __restrict__ w,
                                               unsigned short* __restrict__ wT) {
  int i = blockIdx.x * 256 + threadIdx.x;
  if (i >= CO * CI * KK) return;
  int k = i % KK;
  int ci = (i / KK) & 127;
  int co = i / (KK * CI);
  wT[((size_t)k * CO + co) * CI + ci] = f2bf(w[i]);
}

// ---------------- Kernel A3: w_off f32 -> bf16, layout [tap][oc32][ci], oc>=18 zero ----------------
__global__ __launch_bounds__(256) void k_wprep2(const float* __restrict__ w,
                                                unsigned short* __restrict__ wT2) {
  int i = blockIdx.x * 256 + threadIdx.x;  // 9*32*128 = 36864
  if (i >= 9 * 32 * 128) return;
  int ci = i & 127;
  int oc = (i >> 7) & 31;
  int tap = i >> 12;
  unsigned short v = 0;
  if (oc < 18) v = f2bf(w[((size_t)(oc * 128 + ci)) * 9 + tap]);
  wT2[i] = v;
}

// ---------------- Kernel B: fused deformable sampling + bf16 MFMA GEMM ----------------
__global__ __launch_bounds__(256) void k_main(
    const float* __restrict__ x, const float* __restrict__ offs,
    const unsigned short* __restrict__ wT, float* __restrict__ outp,
    float* __restrict__ stats) {
  __shared__ float xst[32 * 288];        // 32 ci x (12 rows x 24 cols), halo 4
  __shared__ float scoord[KK * 64 * 2];  // ys,xs per (tap,px)
  __shared__ __align__(16) unsigned char samp[64 * 32 * 2];  // bf16 [px][ci_local], XOR-swizzled

  const int bid = blockIdx.x;  // 1024
  const int b = bid >> 8;
  const int rem = bid & 255;
  const int h0 = (rem >> 3) * 4;
  const int w0 = (rem & 7) * 16;
  const int t = threadIdx.x;
  const int l = t & 63;
  const int wv = t >> 6;
  const int colc = l & 15;
  const int kg = l >> 4;
  const int px_s = l;

  // phase 0: coords for all 9 taps
  for (int i = t; i < KK * 64; i += 256) {
    int tap = i >> 6, px = i & 63;
    int h = h0 + (px >> 4), w = w0 + (px & 15);
    float dy = offs[((size_t)(b * 18 + 2 * tap)) * HW + h * WW + w];
    float dx = offs[((size_t)(b * 18 + 2 * tap + 1)) * HW + h * WW + w];
    scoord[i * 2] = (float)(h - 1 + tap / 3) + dy;
    scoord[i * 2 + 1] = (float)(w - 1 + tap % 3) + dx;
  }

  f32x4 acc[4][2];
#pragma unroll
  for (int mf = 0; mf < 4; ++mf)
#pragma unroll
    for (int nf = 0; nf < 2; ++nf) acc[mf][nf] = (f32x4){0.f, 0.f, 0.f, 0.f};

  __syncthreads();

#pragma unroll 1
  for (int cig = 0; cig < 4; ++cig) {
    // stage 32 ci of x into LDS (zero-padded halo)
    const float* xb = x + (size_t)b * CI * HW + (size_t)cig * 32 * HW;
    for (int j = t; j < 32 * 288; j += 256) {
      int ci = j / 288;
      int e = j - ci * 288;
      int r = e / 24;
      int c = e - r * 24;
      int gh = h0 - 4 + r, gw = w0 - 4 + c;
      float v = 0.f;
      if ((unsigned)gh < 128u && (unsigned)gw < 128u) v = xb[ci * HW + gh * WW + gw];
      xst[j] = v;
    }
    __syncthreads();

#pragma unroll 1
    for (int tap = 0; tap < KK; ++tap) {
      // --- sampling: each wave covers all 64 px, ci pairs {2wv,2wv+1}+8it ---
      float2 c2 = *(const float2*)&scoord[(tap * 64 + px_s) * 2];
      float ysv = c2.x, xsv = c2.y;
      float y0f = floorf(ysv), x0f = floorf(xsv);
      float wy = ysv - y0f, wx = xsv - x0f;
      int iy0 = (int)y0f, ix0 = (int)x0f;
      bool vy0 = (unsigned)iy0 < 128u;
      bool vy1 = (unsigned)(iy0 + 1) < 128u;
      bool vx0 = (unsigned)ix0 < 128u;
      bool vx1 = (unsigned)(ix0 + 1) < 128u;
      float wy0 = 1.f - wy, wx0 = 1.f - wx;
      float w00 = wy0 * wx0 * ((vy0 & vx0) ? 1.f : 0.f);
      float w01 = wy0 * wx * ((vy0 & vx1) ? 1.f : 0.f);
      float w10 = wy * wx0 * ((vy1 & vx0) ? 1.f : 0.f);
      float w11 = wy * wx * ((vy1 & vx1) ? 1.f : 0.f);
      int rs = min(max(iy0 - h0 + 4, 0), 10);
      int cs = min(max(ix0 - w0 + 4, 0), 22);
      int sb = rs * 24 + cs;
#pragma unroll
      for (int it = 0; it < 4; ++it) {
        int cl = wv * 2 + it * 8;
        const float* r0 = &xst[cl * 288 + sb];
        const float* r1 = r0 + 288;
        float va = w00 * r0[0] + w01 * r0[1] + w10 * r0[24] + w11 * r0[25];
        float vb = w00 * r1[0] + w01 * r1[1] + w10 * r1[24] + w11 * r1[25];
        unsigned int pk = ((unsigned int)f2bf(vb) << 16) | (unsigned int)f2bf(va);
        int bo = (px_s * 64 + cl * 2) ^ ((px_s & 7) << 4);
        *(unsigned int*)(samp + bo) = pk;
      }
      __syncthreads();
      // --- MFMA: one K=32 step ---
      bf16x8 afr[4];
#pragma unroll
      for (int mf = 0; mf < 4; ++mf) {
        int px = mf * 16 + colc;
        int bo = (px * 64 + kg * 16) ^ ((px & 7) << 4);
        afr[mf] = *(const bf16x8*)(samp + bo);
      }
#pragma unroll
      for (int nf = 0; nf < 2; ++nf) {
        int co = wv * 32 + nf * 16 + colc;
        bf16x8 bfr = *(const bf16x8*)(wT + ((size_t)(tap * CO + co)) * CI + cig * 32 + kg * 8);
#pragma unroll
        for (int mf = 0; mf < 4; ++mf)
          acc[mf][nf] = __builtin_amdgcn_mfma_f32_16x16x32_bf16(afr[mf], bfr, acc[mf][nf], 0, 0, 0);
      }
      __syncthreads();
    }
  }

  // epilogue: BN partial stats + store pre-BN out
#pragma unroll
  for (int nf = 0; nf < 2; ++nf) {
    float s = 0.f, sq = 0.f;
#pragma unroll
    for (int mf = 0; mf < 4; ++mf)
#pragma unroll
      for (int r = 0; r < 4; ++r) {
        float v = acc[mf][nf][r];
        s += v;
        sq += v * v;
      }
    s += __shfl_xor(s, 16);
    s += __shfl_xor(s, 32);
    sq += __shfl_xor(sq, 16);
    sq += __shfl_xor(sq, 32);
    if (kg == 0) {
      int co = wv * 32 + nf * 16 + colc;
      atomicAdd(&stats[co], s);
      atomicAdd(&stats[CO + co], sq);
    }
  }
  const size_t ob = (size_t)b * CO * HW;
#pragma unroll
  for (int mf = 0; mf < 4; ++mf) {
#pragma unroll
    for (int nf = 0; nf < 2; ++nf) {
      int co = wv * 32 + nf * 16 + colc;
      *(f32x4*)&outp[ob + (size_t)co * HW + (h0 + mf) * WW + w0 + kg * 4] = acc[mf][nf];
    }
  }
}

// ---------------- Kernel C: fold stats -> per-channel scale/shift ----------------
__global__ void k_stats(const float* __restrict__ stats, const float* __restrict__ gamma,
                        const float* __restrict__ beta, float* __restrict__ sc) {
  int co = threadIdx.x;
  const float inv = 1.f / 65536.f;
  float mean = stats[co] * inv;
  float var = stats[CO + co] * inv - mean * mean;
  float scale = rsqrtf(var + 1e-3f) * gamma[co];
  sc[co] = scale;
  sc[CO + co] = beta[co] - mean * scale;
}

// ---------------- Kernel D: in-place BN apply + ReLU (float4) ----------------
__global__ __launch_bounds__(256) void k_bn(float* __restrict__ outp,
                                            const float* __restrict__ sc) {
  int i = blockIdx.x * 256 + threadIdx.x;  // f32x4 index, 2097152 total
  f32x4 v = ((const f32x4*)outp)[i];
  int co = (i >> 12) & 127;
  float scale = sc[co], shift = sc[CO + co];
#pragma unroll
  for (int j = 0; j < 4; ++j) {
    float y = v[j] * scale + shift;
    v[j] = y > 0.f ? y : 0.f;
  }
  ((f32x4*)outp)[i] = v;
}

extern "C" void kernel_launch(void* const* d_in, const int* in_sizes, int n_in,
                              void* d_out, int out_size, void* d_ws, size_t ws_size,
                              hipStream_t stream) {
  const float* x = (const float*)d_in[0];
  const float* w_off = (const float*)d_in[1];
  const float* b_off = (const float*)d_in[2];
  const float* w_dcn = (const float*)d_in[3];
  const float* gamma = (const float*)d_in[4];
  const float* beta = (const float*)d_in[5];
  float* out = (float*)d_out;
  char* ws = (char*)d_ws;

  // ws layout: wT bf16 [0, 294912); wT2 bf16 [294912, 368640);
  //            offs f32 [368640, 5087232); stats [5087232, 5088256);
  //            sc [5088256, 5089280)
  unsigned short* wT = (unsigned short*)(ws);
  unsigned short* wT2 = (unsigned short*)(ws + 294912);
  float* offs = (float*)(ws + 368640);
  float* stats = (float*)(ws + 5087232);
  float* sc = (float*)(ws + 5088256);

  hipMemsetAsync(stats, 0, 1024, stream);
  k_wprep<<<576, 256, 0, stream>>>(w_dcn, wT);
  k_wprep2<<<144, 256, 0, stream>>>(w_off, wT2);
  k_offconv_mfma<<<1024, 256, 0, stream>>>(x, wT2, b_off, offs);
  k_main<<<1024, 256, 0, stream>>>(x, offs, wT, out, stats);
  k_stats<<<1, 128, 0, stream>>>(stats, gamma, beta, sc);
  k_bn<<<8192, 256, 0, stream>>>(out, sc);
}